// Round 8
// baseline (268.566 us; speedup 1.0000x reference)
//
#include <hip/hip_runtime.h>
#include <hip/hip_bf16.h>
#include <hip/hip_fp16.h>
#include <math.h>

// N=20000, E=320000, layers: [N,256]@[256,256] GEMMs, HEADS=2, HID=128.
#define NCH 256
#define LEAKY 0.2f

typedef __attribute__((ext_vector_type(8))) short bf16x8;  // 4 VGPRs
typedef __attribute__((ext_vector_type(4))) float f32x4;   // MFMA C/D
typedef _Float16 half2_t __attribute__((ext_vector_type(2)));

static __device__ __forceinline__ ushort f2bf(float f) {
    unsigned u = __float_as_uint(f);
    u += 0x7fffu + ((u >> 16) & 1u);          // RNE
    return (ushort)(u >> 16);
}
static __device__ __forceinline__ float bf2f(ushort h) {
    return __uint_as_float(((unsigned)h) << 16);
}
static __device__ __forceinline__ half2_t u2h2(unsigned u) {
    return __builtin_bit_cast(half2_t, u);
}

// ---------------------------------------------------------------------------
// CSR build: zero -> counts -> scan -> scatter
// ---------------------------------------------------------------------------
__global__ void zero_kernel(int* __restrict__ p, int n) {
    int i = blockIdx.x * 256 + threadIdx.x;
    if (i < n) p[i] = 0;
}

__global__ void count_kernel(const int* __restrict__ ei, int E, int n,
                             int* __restrict__ counts) {
    int tid = blockIdx.x * 256 + threadIdx.x;
    int tot = E + n;
    if (tid >= tot) return;
    int dst = (tid < E) ? ei[E + tid] : (tid - E);
    atomicAdd(&counts[dst], 1);
}

__global__ void scan_kernel(const int* __restrict__ counts,
                            int* __restrict__ offsets,
                            int* __restrict__ cursor, int n) {
    __shared__ int wsum[16];
    int tid  = threadIdx.x;          // 1024 threads = 16 waves
    int lane = tid & 63, w = tid >> 6;
    int carry = 0;
    for (int base = 0; base < n; base += 1024) {
        int idx = base + tid;
        int v = (idx < n) ? counts[idx] : 0;
        int incl = v;
        #pragma unroll
        for (int off = 1; off < 64; off <<= 1) {
            int t2 = __shfl_up(incl, off, 64);
            if (lane >= off) incl += t2;
        }
        if (lane == 63) wsum[w] = incl;
        __syncthreads();
        if (w == 0 && lane < 16) {
            int s = wsum[lane];
            #pragma unroll
            for (int off = 1; off < 16; off <<= 1) {
                int t2 = __shfl_up(s, off, 64);
                if (lane >= off) s += t2;
            }
            wsum[lane] = s;
        }
        __syncthreads();
        int wpre = (w == 0) ? 0 : wsum[w - 1];
        int excl = carry + wpre + incl - v;
        if (idx < n) { offsets[idx] = excl; cursor[idx] = excl; }
        carry += wsum[15];
        __syncthreads();
    }
    if (tid == 0) offsets[n] = carry;
}

__global__ void scatter_kernel(const int* __restrict__ ei, int E, int n,
                               int* __restrict__ cursor,
                               int* __restrict__ csr_src) {
    int tid = blockIdx.x * 256 + threadIdx.x;
    int tot = E + n;
    if (tid >= tot) return;
    int src, dst;
    if (tid < E) { src = ei[tid]; dst = ei[E + tid]; }
    else         { src = dst = tid - E; }
    int pos = atomicAdd(&cursor[dst], 1);
    csr_src[pos] = src;
}

// ---------------------------------------------------------------------------
// fp32 -> bf16 hi/lo split (layer-1 input x only)
// ---------------------------------------------------------------------------
__global__ void split_kernel(const float* __restrict__ in,
                             ushort* __restrict__ hi, ushort* __restrict__ lo,
                             int n4) {
    int i = blockIdx.x * 256 + threadIdx.x;
    if (i >= n4) return;
    float4 v = ((const float4*)in)[i];
    ushort h0 = f2bf(v.x), h1 = f2bf(v.y), h2 = f2bf(v.z), h3 = f2bf(v.w);
    ((ushort4*)hi)[i] = make_ushort4(h0, h1, h2, h3);
    ((ushort4*)lo)[i] = make_ushort4(f2bf(v.x - bf2f(h0)), f2bf(v.y - bf2f(h1)),
                                     f2bf(v.z - bf2f(h2)), f2bf(v.w - bf2f(h3)));
}

// ---------------------------------------------------------------------------
// Weight transpose+split: W[256,256] -> Wt[256,256] (n-major) bf16 hi/lo.
// ---------------------------------------------------------------------------
struct WPtrs { const float* w[6]; };
__global__ __launch_bounds__(1024) void wsplit_kernel(WPtrs p,
        ushort* __restrict__ hi, ushort* __restrict__ lo) {
    __shared__ float tile[32][33];
    int m = blockIdx.z;
    const float* W = p.w[m];
    size_t base = (size_t)m * 65536;
    int k = blockIdx.y * 32 + threadIdx.y;
    int n = blockIdx.x * 32 + threadIdx.x;
    tile[threadIdx.y][threadIdx.x] = W[k * NCH + n];
    __syncthreads();
    int on = blockIdx.x * 32 + threadIdx.y;
    int ok = blockIdx.y * 32 + threadIdx.x;
    float v = tile[threadIdx.x][threadIdx.y];
    ushort h = f2bf(v);
    hi[base + (size_t)on * NCH + ok] = h;
    lo[base + (size_t)on * NCH + ok] = f2bf(v - bf2f(h));
}

// ---------------------------------------------------------------------------
// MFMA dual GEMM with bf16 hi/lo split (3-product fp32-accurate).
// Flat grid with L2-reuse swizzle (stripes of 32 = 8 row-tiles x 4 cbs).
// ---------------------------------------------------------------------------
#define LDK 40
__global__ __launch_bounds__(256) void dual_gemm_mfma(
        const ushort* __restrict__ Ahi, const ushort* __restrict__ Alo,
        const ushort* __restrict__ Bthi, const ushort* __restrict__ Btlo,
        __half* __restrict__ xlh, float* __restrict__ xr, int M) {
    __shared__ ushort As[2][128 * LDK];
    __shared__ ushort Bs[2][128 * LDK];
    int b = blockIdx.x;
    int stripe = b >> 5;
    int wslot  = b & 31;
    int rt = (stripe << 3) + (wslot & 7);
    int cb = wslot >> 3;
    int row0 = rt * 128;
    if (row0 >= M) return;
    const ushort* Bh = Bthi + (size_t)(cb >> 1) * 65536;
    const ushort* Bl = Btlo + (size_t)(cb >> 1) * 65536;
    int col0 = (cb & 1) * 128;
    int t = threadIdx.x;
    int lane = t & 63, w = t >> 6;
    int wr = w >> 1, wc = w & 1;
    int l15 = lane & 15, l4 = lane >> 4;

    f32x4 acc[4][4];
    #pragma unroll
    for (int i = 0; i < 4; ++i)
        #pragma unroll
        for (int j = 0; j < 4; ++j) acc[i][j] = (f32x4){0.f, 0.f, 0.f, 0.f};

    int r0 = t >> 2,          q0 = (t & 3) * 8;
    int r1 = (t + 256) >> 2,  q1 = ((t + 256) & 3) * 8;

    for (int k0 = 0; k0 < 256; k0 += 32) {
        uint4 z = make_uint4(0, 0, 0, 0);
        uint4 a0h = z, a0l = z, a1h = z, a1l = z;
        if (row0 + r0 < M) {
            a0h = *(const uint4*)&Ahi[(size_t)(row0 + r0) * NCH + k0 + q0];
            a0l = *(const uint4*)&Alo[(size_t)(row0 + r0) * NCH + k0 + q0];
        }
        if (row0 + r1 < M) {
            a1h = *(const uint4*)&Ahi[(size_t)(row0 + r1) * NCH + k0 + q1];
            a1l = *(const uint4*)&Alo[(size_t)(row0 + r1) * NCH + k0 + q1];
        }
        uint4 b0h = *(const uint4*)&Bh[(size_t)(col0 + r0) * NCH + k0 + q0];
        uint4 b0l = *(const uint4*)&Bl[(size_t)(col0 + r0) * NCH + k0 + q0];
        uint4 b1h = *(const uint4*)&Bh[(size_t)(col0 + r1) * NCH + k0 + q1];
        uint4 b1l = *(const uint4*)&Bl[(size_t)(col0 + r1) * NCH + k0 + q1];
        __syncthreads();
        *(uint4*)&As[0][r0 * LDK + q0] = a0h;
        *(uint4*)&As[1][r0 * LDK + q0] = a0l;
        *(uint4*)&As[0][r1 * LDK + q1] = a1h;
        *(uint4*)&As[1][r1 * LDK + q1] = a1l;
        *(uint4*)&Bs[0][r0 * LDK + q0] = b0h;
        *(uint4*)&Bs[1][r0 * LDK + q0] = b0l;
        *(uint4*)&Bs[0][r1 * LDK + q1] = b1h;
        *(uint4*)&Bs[1][r1 * LDK + q1] = b1l;
        __syncthreads();

        bf16x8 af[4][2], bq[4][2];
        #pragma unroll
        for (int fm = 0; fm < 4; ++fm) {
            int addr = (wr * 64 + fm * 16 + l15) * LDK + l4 * 8;
            af[fm][0] = *(const bf16x8*)&As[0][addr];
            af[fm][1] = *(const bf16x8*)&As[1][addr];
        }
        #pragma unroll
        for (int fn = 0; fn < 4; ++fn) {
            int addr = (wc * 64 + fn * 16 + l15) * LDK + l4 * 8;
            bq[fn][0] = *(const bf16x8*)&Bs[0][addr];
            bq[fn][1] = *(const bf16x8*)&Bs[1][addr];
        }
        #pragma unroll
        for (int fm = 0; fm < 4; ++fm)
            #pragma unroll
            for (int fn = 0; fn < 4; ++fn) {
                acc[fm][fn] = __builtin_amdgcn_mfma_f32_16x16x32_bf16(
                    af[fm][0], bq[fn][0], acc[fm][fn], 0, 0, 0);
                acc[fm][fn] = __builtin_amdgcn_mfma_f32_16x16x32_bf16(
                    af[fm][0], bq[fn][1], acc[fm][fn], 0, 0, 0);
                acc[fm][fn] = __builtin_amdgcn_mfma_f32_16x16x32_bf16(
                    af[fm][1], bq[fn][0], acc[fm][fn], 0, 0, 0);
            }
    }

    #pragma unroll
    for (int fm = 0; fm < 4; ++fm)
        #pragma unroll
        for (int fn = 0; fn < 4; ++fn) {
            int col = col0 + wc * 64 + fn * 16 + l15;
            #pragma unroll
            for (int r = 0; r < 4; ++r) {
                int row = row0 + wr * 64 + fm * 16 + l4 * 4 + r;
                if (row < M) {
                    if (cb < 2)
                        xlh[(size_t)row * NCH + col] = __float2half_rn(acc[fm][fn][r]);
                    else
                        xr[(size_t)row * NCH + col] = acc[fm][fn][r];
                }
            }
        }
}

// ---------------------------------------------------------------------------
// GAT aggregation v6: persistent waves (2500 blocks -> exactly 2 nodes/wave),
// half-wave pair layout + 1-deep software pipeline (prefetch next pair's
// indices and rows before computing the current pair -> 4 rows in flight).
// lane = 32*el + l; channels [8l,8l+8); l 0..15 = head0, 16..31 = head1.
// ---------------------------------------------------------------------------
static __device__ __forceinline__ float edge_dot(
        const uint4& r, const half2_t* xrh, const half2_t* atth) {
    const half2_t zh = (half2_t){(_Float16)0.f, (_Float16)0.f};
    const half2_t ch = (half2_t){(_Float16)LEAKY, (_Float16)LEAKY};
    float p = 0.f;
    #pragma unroll
    for (int q = 0; q < 4; ++q) {
        unsigned u = (&r.x)[q];
        half2_t t = u2h2(u) + xrh[q];
        half2_t m = __builtin_elementwise_max(t, zh) +
                    ch * __builtin_elementwise_min(t, zh);
        p = __builtin_amdgcn_fdot2(m, atth[q], p, false);
    }
    return p;
}

template <int LAST>
__global__ __launch_bounds__(256) void gat_agg6(
        const __half* __restrict__ xlh, const float* __restrict__ xr,
        const float* __restrict__ att, const float* __restrict__ bias,
        const int* __restrict__ offsets, const int* __restrict__ csr_src,
        ushort* __restrict__ hhi, ushort* __restrict__ hlo,
        const float* __restrict__ Wout, const float* __restrict__ bout,
        float* __restrict__ out, int nNodes) {
    int wid  = threadIdx.x >> 6;
    int lane = threadIdx.x & 63;
    int el = lane >> 5;
    int l  = lane & 31;
    int c0 = l * 8;

    half2_t atth[4];
    {
        float a8[8];
        *(float4*)&a8[0] = *(const float4*)&att[c0];
        *(float4*)&a8[4] = *(const float4*)&att[c0 + 4];
        #pragma unroll
        for (int q = 0; q < 4; ++q)
            atth[q] = (half2_t){(_Float16)a8[2 * q], (_Float16)a8[2 * q + 1]};
    }

    int stride = gridDim.x << 2;
    for (int node0 = (blockIdx.x << 2) + wid; node0 < nNodes; node0 += stride) {
        int node = __builtin_amdgcn_readfirstlane(node0);
        half2_t xrh[4];
        {
            float x8[8];
            *(float4*)&x8[0] = *(const float4*)&xr[(size_t)node * NCH + c0];
            *(float4*)&x8[4] = *(const float4*)&xr[(size_t)node * NCH + c0 + 4];
            #pragma unroll
            for (int q = 0; q < 4; ++q)
                xrh[q] = (half2_t){(_Float16)x8[2 * q], (_Float16)x8[2 * q + 1]};
        }

        int begin = offsets[node], end = offsets[node + 1];
        float denom = 0.f;
        float acc8[8];
        #pragma unroll
        for (int c = 0; c < 8; ++c) acc8[c] = 0.f;

        // ---- prologue: load pair 0
        uint4 rA0, rB0;
        {
            int j1 = begin + 1 < end ? begin + 1 : end - 1;
            int j2 = begin + 2 < end ? begin + 2 : end - 1;
            int j3 = begin + 3 < end ? begin + 3 : end - 1;
            int i0 = csr_src[begin], i1 = csr_src[j1];
            int i2 = csr_src[j2],    i3 = csr_src[j3];
            int sA = el ? i1 : i0;
            int sB = el ? i3 : i2;
            rA0 = *(const uint4*)&xlh[(size_t)sA * NCH + c0];
            rB0 = *(const uint4*)&xlh[(size_t)sB * NCH + c0];
        }

        for (int j = begin; j < end; j += 4) {
            // ---- prefetch pair j+4 (wave-uniform guard)
            uint4 rA1, rB1;
            int jn = j + 4;
            if (jn < end) {
                int j1 = jn + 1 < end ? jn + 1 : end - 1;
                int j2 = jn + 2 < end ? jn + 2 : end - 1;
                int j3 = jn + 3 < end ? jn + 3 : end - 1;
                int i0 = csr_src[jn], i1 = csr_src[j1];
                int i2 = csr_src[j2], i3 = csr_src[j3];
                int sA = el ? i1 : i0;
                int sB = el ? i3 : i2;
                rA1 = *(const uint4*)&xlh[(size_t)sA * NCH + c0];
                rB1 = *(const uint4*)&xlh[(size_t)sB * NCH + c0];
            }
            // ---- compute on pair j
            float pA = edge_dot(rA0, xrh, atth);
            float pB = edge_dot(rB0, xrh, atth);
            #pragma unroll
            for (int off = 1; off < 16; off <<= 1) {
                pA += __shfl_xor(pA, off);
                pB += __shfl_xor(pB, off);
            }
            float exA = (j + el < end)     ? __expf(pA) : 0.f;
            float exB = (j + 2 + el < end) ? __expf(pB) : 0.f;
            denom += exA + exB;
            #pragma unroll
            for (int q = 0; q < 4; ++q) {
                float2 fa = __half22float2(*(const __half2*)&(&rA0.x)[q]);
                float2 fb = __half22float2(*(const __half2*)&(&rB0.x)[q]);
                acc8[2 * q]     = fmaf(exA, fa.x, acc8[2 * q]);
                acc8[2 * q + 1] = fmaf(exA, fa.y, acc8[2 * q + 1]);
                acc8[2 * q]     = fmaf(exB, fb.x, acc8[2 * q]);
                acc8[2 * q + 1] = fmaf(exB, fb.y, acc8[2 * q + 1]);
            }
            rA0 = rA1; rB0 = rB1;
        }

        // combine edge-halves
        #pragma unroll
        for (int c = 0; c < 8; ++c) acc8[c] += __shfl_xor(acc8[c], 32);
        denom += __shfl_xor(denom, 32);
        float rd = 1.0f / denom;

        float o8[8], bi8[8];
        *(float4*)&bi8[0] = *(const float4*)&bias[c0];
        *(float4*)&bi8[4] = *(const float4*)&bias[c0 + 4];
        #pragma unroll
        for (int c = 0; c < 8; ++c)
            o8[c] = fmaxf(fmaf(acc8[c], rd, bi8[c]), 0.f);

        if (!LAST) {
            if (el == 0) {
                ushort h8[8], lo8[8];
                #pragma unroll
                for (int c = 0; c < 8; ++c) {
                    h8[c]  = f2bf(o8[c]);
                    lo8[c] = f2bf(o8[c] - bf2f(h8[c]));
                }
                *(uint4*)&hhi[(size_t)node * NCH + c0] = *(uint4*)&h8[0];
                *(uint4*)&hlo[(size_t)node * NCH + c0] = *(uint4*)&lo8[0];
            }
        } else {
            float p0 = 0.f, p1 = 0.f, p2 = 0.f, p3 = 0.f;
            #pragma unroll
            for (int c = 0; c < 8; ++c) {
                float4 w4 = *(const float4*)&Wout[(size_t)(c0 + c) * 4];
                p0 = fmaf(o8[c], w4.x, p0);
                p1 = fmaf(o8[c], w4.y, p1);
                p2 = fmaf(o8[c], w4.z, p2);
                p3 = fmaf(o8[c], w4.w, p3);
            }
            #pragma unroll
            for (int off = 1; off < 32; off <<= 1) {
                p0 += __shfl_xor(p0, off);
                p1 += __shfl_xor(p1, off);
                p2 += __shfl_xor(p2, off);
                p3 += __shfl_xor(p3, off);
            }
            if (lane == 0) {
                float4 r;
                r.x = p0 + bout[0]; r.y = p1 + bout[1];
                r.z = p2 + bout[2]; r.w = p3 + bout[3];
                *(float4*)&out[(size_t)node * 4] = r;
            }
        }
    }
}

// ---------------------------------------------------------------------------
extern "C" void kernel_launch(void* const* d_in, const int* in_sizes, int n_in,
                              void* d_out, int out_size, void* d_ws, size_t ws_size,
                              hipStream_t stream) {
    const float* x  = (const float*)d_in[0];
    const int*   ei = (const int*)d_in[1];
    const float* Wl[3]  = {(const float*)d_in[2], (const float*)d_in[6],  (const float*)d_in[10]};
    const float* Wr[3]  = {(const float*)d_in[3], (const float*)d_in[7],  (const float*)d_in[11]};
    const float* att[3] = {(const float*)d_in[4], (const float*)d_in[8],  (const float*)d_in[12]};
    const float* bb[3]  = {(const float*)d_in[5], (const float*)d_in[9],  (const float*)d_in[13]};
    const float* Wout = (const float*)d_in[14];
    const float* bout = (const float*)d_in[15];

    int Nn   = in_sizes[0] / NCH;       // 20000
    int E    = in_sizes[1] / 2;         // 320000
    int Etot = E + Nn;

    size_t NEf = (size_t)Nn * NCH;
    __half* xlh  = (__half*)d_ws;                  // NEf halves
    float*  xr   = (float*)(xlh + NEf);
    ushort* pAhi = (ushort*)(xr + NEf);
    ushort* pAlo = pAhi + NEf;
    ushort* pBhi = pAlo + NEf;
    ushort* pBlo = pBhi + NEf;
    ushort* wthi = pBlo + NEf;                     // 6 * 65536
    ushort* wtlo = wthi + 6 * 65536;
    int*   counts  = (int*)(wtlo + 6 * 65536);
    int*   offsets = counts + Nn;
    int*   cursor  = offsets + (Nn + 1);
    int*   csr_src = cursor + Nn;

    zero_kernel<<<(Nn + 255) / 256, 256, 0, stream>>>(counts, Nn);
    int eblocks = (Etot + 255) / 256;
    count_kernel<<<eblocks, 256, 0, stream>>>(ei, E, Nn, counts);
    scan_kernel<<<1, 1024, 0, stream>>>(counts, offsets, cursor, Nn);
    scatter_kernel<<<eblocks, 256, 0, stream>>>(ei, E, Nn, cursor, csr_src);

    WPtrs wp = {{Wl[0], Wr[0], Wl[1], Wr[1], Wl[2], Wr[2]}};
    wsplit_kernel<<<dim3(8, 8, 6), dim3(32, 32), 0, stream>>>(wp, wthi, wtlo);

    int n4 = (int)(NEf / 4);
    split_kernel<<<(n4 + 255) / 256, 256, 0, stream>>>(x, pAhi, pAlo, n4);

    int nrt = (Nn + 127) / 128;                    // 157 row tiles
    int prt = ((nrt + 7) / 8) * 8;                 // padded to 8
    int gblocks = prt * 4;                         // 640
    int nblocks = 2500;                            // 10000 waves = 2 nodes each
    if (nblocks > (Nn + 3) / 4) nblocks = (Nn + 3) / 4;

    ushort* curHi = pAhi; ushort* curLo = pAlo;
    ushort* nxtHi = pBhi; ushort* nxtLo = pBlo;
    for (int l = 0; l < 3; ++l) {
        dual_gemm_mfma<<<gblocks, 256, 0, stream>>>(
            curHi, curLo, wthi + (size_t)l * 2 * 65536, wtlo + (size_t)l * 2 * 65536,
            xlh, xr, Nn);
        if (l < 2) {
            gat_agg6<0><<<nblocks, 256, 0, stream>>>(xlh, xr, att[l], bb[l],
                offsets, csr_src, nxtHi, nxtLo, nullptr, nullptr, nullptr, Nn);
        } else {
            gat_agg6<1><<<nblocks, 256, 0, stream>>>(xlh, xr, att[l], bb[l],
                offsets, csr_src, nullptr, nullptr, Wout, bout, (float*)d_out, Nn);
        }
        ushort* th = curHi; ushort* tl = curLo;
        curHi = nxtHi; curLo = nxtLo; nxtHi = th; nxtLo = tl;
    }
}

// Round 9
// 265.478 us; speedup vs baseline: 1.0116x; 1.0116x over previous
//
#include <hip/hip_runtime.h>
#include <hip/hip_bf16.h>
#include <hip/hip_fp16.h>
#include <math.h>

// N=20000, E=320000, layers: [N,256]@[256,256] GEMMs, HEADS=2, HID=128.
#define NCH 256
#define LEAKY 0.2f

typedef __attribute__((ext_vector_type(8))) _Float16 half8_t;  // 4 VGPRs
typedef __attribute__((ext_vector_type(2))) _Float16 half2_t;
typedef __attribute__((ext_vector_type(4))) float f32x4;       // MFMA C/D

static __device__ __forceinline__ half2_t u2h2(unsigned u) {
    return __builtin_bit_cast(half2_t, u);
}

// ---------------------------------------------------------------------------
// CSR build: zero -> counts -> scan -> scatter
// ---------------------------------------------------------------------------
__global__ void zero_kernel(int* __restrict__ p, int n) {
    int i = blockIdx.x * 256 + threadIdx.x;
    if (i < n) p[i] = 0;
}

__global__ void count_kernel(const int* __restrict__ ei, int E, int n,
                             int* __restrict__ counts) {
    int tid = blockIdx.x * 256 + threadIdx.x;
    int tot = E + n;
    if (tid >= tot) return;
    int dst = (tid < E) ? ei[E + tid] : (tid - E);
    atomicAdd(&counts[dst], 1);
}

__global__ void scan_kernel(const int* __restrict__ counts,
                            int* __restrict__ offsets,
                            int* __restrict__ cursor, int n) {
    __shared__ int wsum[16];
    int tid  = threadIdx.x;          // 1024 threads = 16 waves
    int lane = tid & 63, w = tid >> 6;
    int carry = 0;
    for (int base = 0; base < n; base += 1024) {
        int idx = base + tid;
        int v = (idx < n) ? counts[idx] : 0;
        int incl = v;
        #pragma unroll
        for (int off = 1; off < 64; off <<= 1) {
            int t2 = __shfl_up(incl, off, 64);
            if (lane >= off) incl += t2;
        }
        if (lane == 63) wsum[w] = incl;
        __syncthreads();
        if (w == 0 && lane < 16) {
            int s = wsum[lane];
            #pragma unroll
            for (int off = 1; off < 16; off <<= 1) {
                int t2 = __shfl_up(s, off, 64);
                if (lane >= off) s += t2;
            }
            wsum[lane] = s;
        }
        __syncthreads();
        int wpre = (w == 0) ? 0 : wsum[w - 1];
        int excl = carry + wpre + incl - v;
        if (idx < n) { offsets[idx] = excl; cursor[idx] = excl; }
        carry += wsum[15];
        __syncthreads();
    }
    if (tid == 0) offsets[n] = carry;
}

__global__ void scatter_kernel(const int* __restrict__ ei, int E, int n,
                               int* __restrict__ cursor,
                               int* __restrict__ csr_src) {
    int tid = blockIdx.x * 256 + threadIdx.x;
    int tot = E + n;
    if (tid >= tot) return;
    int src, dst;
    if (tid < E) { src = ei[tid]; dst = ei[E + tid]; }
    else         { src = dst = tid - E; }
    int pos = atomicAdd(&cursor[dst], 1);
    csr_src[pos] = src;
}

// ---------------------------------------------------------------------------
// fp32 -> fp16 hi/lo split (layer-1 input x only). hi+lo covers 22 bits.
// ---------------------------------------------------------------------------
__global__ void split_kernel(const float* __restrict__ in,
                             __half* __restrict__ hi, __half* __restrict__ lo,
                             int n4) {
    int i = blockIdx.x * 256 + threadIdx.x;
    if (i >= n4) return;
    float4 v = ((const float4*)in)[i];
    __half h0 = __float2half_rn(v.x), h1 = __float2half_rn(v.y);
    __half h2 = __float2half_rn(v.z), h3 = __float2half_rn(v.w);
    ushort4 hv = make_ushort4(__half_as_ushort(h0), __half_as_ushort(h1),
                              __half_as_ushort(h2), __half_as_ushort(h3));
    ushort4 lv = make_ushort4(
        __half_as_ushort(__float2half_rn(v.x - __half2float(h0))),
        __half_as_ushort(__float2half_rn(v.y - __half2float(h1))),
        __half_as_ushort(__float2half_rn(v.z - __half2float(h2))),
        __half_as_ushort(__float2half_rn(v.w - __half2float(h3))));
    ((ushort4*)hi)[i] = hv;
    ((ushort4*)lo)[i] = lv;
}

// ---------------------------------------------------------------------------
// Weight transpose: W[256,256] (k-major) -> Wt[256,256] (n-major) fp16.
// ---------------------------------------------------------------------------
struct WPtrs { const float* w[6]; };
__global__ __launch_bounds__(1024) void wsplit_kernel(WPtrs p,
        __half* __restrict__ wt) {
    __shared__ float tile[32][33];
    int m = blockIdx.z;
    const float* W = p.w[m];
    size_t base = (size_t)m * 65536;
    int k = blockIdx.y * 32 + threadIdx.y;
    int n = blockIdx.x * 32 + threadIdx.x;
    tile[threadIdx.y][threadIdx.x] = W[k * NCH + n];
    __syncthreads();
    int on = blockIdx.x * 32 + threadIdx.y;
    int ok = blockIdx.y * 32 + threadIdx.x;
    wt[base + (size_t)on * NCH + ok] = __float2half_rn(tile[threadIdx.x][threadIdx.y]);
}

// ---------------------------------------------------------------------------
// MFMA dual GEMM, fp16 2-product split: C = Ahi*B + Alo*B (B single fp16).
// Flat grid with L2-reuse swizzle (stripes of 32 = 8 row-tiles x 4 cbs).
// xl written fp16 (gather side), xr fp32.
// ---------------------------------------------------------------------------
#define LDK 40
__global__ __launch_bounds__(256) void dual_gemm_mfma(
        const __half* __restrict__ Ahi, const __half* __restrict__ Alo,
        const __half* __restrict__ Bt,
        __half* __restrict__ xlh, float* __restrict__ xr, int M) {
    __shared__ ushort As[2][128 * LDK];
    __shared__ ushort Bs[128 * LDK];
    int b = blockIdx.x;
    int stripe = b >> 5;
    int wslot  = b & 31;
    int rt = (stripe << 3) + (wslot & 7);
    int cb = wslot >> 3;
    int row0 = rt * 128;
    if (row0 >= M) return;
    const __half* Bm = Bt + (size_t)(cb >> 1) * 65536;
    int col0 = (cb & 1) * 128;
    int t = threadIdx.x;
    int lane = t & 63, w = t >> 6;
    int wr = w >> 1, wc = w & 1;
    int l15 = lane & 15, l4 = lane >> 4;

    f32x4 acc[4][4];
    #pragma unroll
    for (int i = 0; i < 4; ++i)
        #pragma unroll
        for (int j = 0; j < 4; ++j) acc[i][j] = (f32x4){0.f, 0.f, 0.f, 0.f};

    int r0 = t >> 2,          q0 = (t & 3) * 8;
    int r1 = (t + 256) >> 2,  q1 = ((t + 256) & 3) * 8;

    for (int k0 = 0; k0 < 256; k0 += 32) {
        uint4 z = make_uint4(0, 0, 0, 0);
        uint4 a0h = z, a0l = z, a1h = z, a1l = z;
        if (row0 + r0 < M) {
            a0h = *(const uint4*)&Ahi[(size_t)(row0 + r0) * NCH + k0 + q0];
            a0l = *(const uint4*)&Alo[(size_t)(row0 + r0) * NCH + k0 + q0];
        }
        if (row0 + r1 < M) {
            a1h = *(const uint4*)&Ahi[(size_t)(row0 + r1) * NCH + k0 + q1];
            a1l = *(const uint4*)&Alo[(size_t)(row0 + r1) * NCH + k0 + q1];
        }
        uint4 b0 = *(const uint4*)&Bm[(size_t)(col0 + r0) * NCH + k0 + q0];
        uint4 b1 = *(const uint4*)&Bm[(size_t)(col0 + r1) * NCH + k0 + q1];
        __syncthreads();
        *(uint4*)&As[0][r0 * LDK + q0] = a0h;
        *(uint4*)&As[1][r0 * LDK + q0] = a0l;
        *(uint4*)&As[0][r1 * LDK + q1] = a1h;
        *(uint4*)&As[1][r1 * LDK + q1] = a1l;
        *(uint4*)&Bs[r0 * LDK + q0] = b0;
        *(uint4*)&Bs[r1 * LDK + q1] = b1;
        __syncthreads();

        half8_t af[4][2], bq[4];
        #pragma unroll
        for (int fm = 0; fm < 4; ++fm) {
            int addr = (wr * 64 + fm * 16 + l15) * LDK + l4 * 8;
            af[fm][0] = *(const half8_t*)&As[0][addr];
            af[fm][1] = *(const half8_t*)&As[1][addr];
        }
        #pragma unroll
        for (int fn = 0; fn < 4; ++fn) {
            int addr = (wc * 64 + fn * 16 + l15) * LDK + l4 * 8;
            bq[fn] = *(const half8_t*)&Bs[addr];
        }
        #pragma unroll
        for (int fm = 0; fm < 4; ++fm)
            #pragma unroll
            for (int fn = 0; fn < 4; ++fn) {
                acc[fm][fn] = __builtin_amdgcn_mfma_f32_16x16x32_f16(
                    af[fm][0], bq[fn], acc[fm][fn], 0, 0, 0);
                acc[fm][fn] = __builtin_amdgcn_mfma_f32_16x16x32_f16(
                    af[fm][1], bq[fn], acc[fm][fn], 0, 0, 0);
            }
    }

    #pragma unroll
    for (int fm = 0; fm < 4; ++fm)
        #pragma unroll
        for (int fn = 0; fn < 4; ++fn) {
            int col = col0 + wc * 64 + fn * 16 + l15;
            #pragma unroll
            for (int r = 0; r < 4; ++r) {
                int row = row0 + wr * 64 + fm * 16 + l4 * 4 + r;
                if (row < M) {
                    if (cb < 2)
                        xlh[(size_t)row * NCH + col] = __float2half_rn(acc[fm][fn][r]);
                    else
                        xr[(size_t)row * NCH + col] = acc[fm][fn][r];
                }
            }
        }
}

// ---------------------------------------------------------------------------
// GAT aggregation v7: quarter-wave layout, 4 edges per wave-iteration.
// lane = 16*eq + l16; eq = edge slot (0..3), l16 = channel-lane,
// channels [16*l16, 16*l16+16). Head0 = l16 0..7, head1 = l16 8..15
// (3-step shfl reduce within 8 lanes). Persistent grid-stride waves.
// ---------------------------------------------------------------------------
template <int LAST>
__global__ __launch_bounds__(256) void gat_agg7(
        const __half* __restrict__ xlh, const float* __restrict__ xr,
        const float* __restrict__ att, const float* __restrict__ bias,
        const int* __restrict__ offsets, const int* __restrict__ csr_src,
        __half* __restrict__ hhi, __half* __restrict__ hlo,
        const float* __restrict__ Wout, const float* __restrict__ bout,
        float* __restrict__ out, int nNodes) {
    int wid  = threadIdx.x >> 6;
    int lane = threadIdx.x & 63;
    int eq  = lane >> 4;         // edge slot 0..3
    int l16 = lane & 15;         // channel-lane
    int c0 = l16 * 16;

    half2_t atth[8];
    {
        float a16[16];
        #pragma unroll
        for (int q = 0; q < 4; ++q)
            *(float4*)&a16[4 * q] = *(const float4*)&att[c0 + 4 * q];
        #pragma unroll
        for (int q = 0; q < 8; ++q)
            atth[q] = (half2_t){(_Float16)a16[2 * q], (_Float16)a16[2 * q + 1]};
    }

    const half2_t zh = (half2_t){(_Float16)0.f, (_Float16)0.f};
    const half2_t ch = (half2_t){(_Float16)LEAKY, (_Float16)LEAKY};

    int stride = gridDim.x << 2;
    for (int node0 = (blockIdx.x << 2) + wid; node0 < nNodes; node0 += stride) {
        int node = __builtin_amdgcn_readfirstlane(node0);
        half2_t xrh[8];
        {
            float x16[16];
            #pragma unroll
            for (int q = 0; q < 4; ++q)
                *(float4*)&x16[4 * q] = *(const float4*)&xr[(size_t)node * NCH + c0 + 4 * q];
            #pragma unroll
            for (int q = 0; q < 8; ++q)
                xrh[q] = (half2_t){(_Float16)x16[2 * q], (_Float16)x16[2 * q + 1]};
        }

        int begin = offsets[node], end = offsets[node + 1];
        float denom = 0.f;
        float acc[16];
        #pragma unroll
        for (int c = 0; c < 16; ++c) acc[c] = 0.f;

        for (int j = begin; j < end; j += 4) {
            int j1 = j + 1 < end ? j + 1 : end - 1;
            int j2 = j + 2 < end ? j + 2 : end - 1;
            int j3 = j + 3 < end ? j + 3 : end - 1;
            int i0 = csr_src[j];               // uniform -> s_load
            int i1 = csr_src[j1];
            int i2 = csr_src[j2];
            int i3 = csr_src[j3];
            int idx = i0;
            if (eq == 1) idx = i1;
            if (eq == 2) idx = i2;
            if (eq == 3) idx = i3;
            bool val = (j + eq) < end;

            const __half* row = xlh + (size_t)idx * NCH + c0;
            uint4 r0 = *(const uint4*)row;
            uint4 r1 = *(const uint4*)(row + 8);

            float p = 0.f;
            #pragma unroll
            for (int q = 0; q < 4; ++q) {
                half2_t tv = u2h2((&r0.x)[q]) + xrh[q];
                half2_t m = __builtin_elementwise_max(tv, zh) +
                            ch * __builtin_elementwise_min(tv, zh);
                p = __builtin_amdgcn_fdot2(m, atth[q], p, false);
            }
            #pragma unroll
            for (int q = 0; q < 4; ++q) {
                half2_t tv = u2h2((&r1.x)[q]) + xrh[4 + q];
                half2_t m = __builtin_elementwise_max(tv, zh) +
                            ch * __builtin_elementwise_min(tv, zh);
                p = __builtin_amdgcn_fdot2(m, atth[4 + q], p, false);
            }
            p += __shfl_xor(p, 1);
            p += __shfl_xor(p, 2);
            p += __shfl_xor(p, 4);
            float ex = val ? __expf(p) : 0.f;
            denom += ex;
            #pragma unroll
            for (int q = 0; q < 4; ++q) {
                float2 f = __half22float2(*(const __half2*)&(&r0.x)[q]);
                acc[2 * q]     = fmaf(ex, f.x, acc[2 * q]);
                acc[2 * q + 1] = fmaf(ex, f.y, acc[2 * q + 1]);
            }
            #pragma unroll
            for (int q = 0; q < 4; ++q) {
                float2 f = __half22float2(*(const __half2*)&(&r1.x)[q]);
                acc[8 + 2 * q] = fmaf(ex, f.x, acc[8 + 2 * q]);
                acc[9 + 2 * q] = fmaf(ex, f.y, acc[9 + 2 * q]);
            }
        }

        // combine the 4 edge-slot groups (same l16/head across groups)
        #pragma unroll
        for (int c = 0; c < 16; ++c) {
            acc[c] += __shfl_xor(acc[c], 16);
            acc[c] += __shfl_xor(acc[c], 32);
        }
        denom += __shfl_xor(denom, 16);
        denom += __shfl_xor(denom, 32);
        float rd = 1.0f / denom;

        if (!LAST) {
            if (eq == 0) {
                float bi16[16];
                #pragma unroll
                for (int q = 0; q < 4; ++q)
                    *(float4*)&bi16[4 * q] = *(const float4*)&bias[c0 + 4 * q];
                ushort h16[16], l16v[16];
                #pragma unroll
                for (int c = 0; c < 16; ++c) {
                    float o = fmaxf(fmaf(acc[c], rd, bi16[c]), 0.f);
                    __half h = __float2half_rn(o);
                    h16[c]  = __half_as_ushort(h);
                    l16v[c] = __half_as_ushort(__float2half_rn(o - __half2float(h)));
                }
                *(uint4*)&hhi[(size_t)node * NCH + c0]     = *(uint4*)&h16[0];
                *(uint4*)&hhi[(size_t)node * NCH + c0 + 8] = *(uint4*)&h16[8];
                *(uint4*)&hlo[(size_t)node * NCH + c0]     = *(uint4*)&l16v[0];
                *(uint4*)&hlo[(size_t)node * NCH + c0 + 8] = *(uint4*)&l16v[8];
            }
        } else {
            float p0 = 0.f, p1 = 0.f, p2 = 0.f, p3 = 0.f;
            if (eq == 0) {
                float bi16[16];
                #pragma unroll
                for (int q = 0; q < 4; ++q)
                    *(float4*)&bi16[4 * q] = *(const float4*)&bias[c0 + 4 * q];
                #pragma unroll
                for (int c = 0; c < 16; ++c) {
                    float o = fmaxf(fmaf(acc[c], rd, bi16[c]), 0.f);
                    float4 w4 = *(const float4*)&Wout[(size_t)(c0 + c) * 4];
                    p0 = fmaf(o, w4.x, p0);
                    p1 = fmaf(o, w4.y, p1);
                    p2 = fmaf(o, w4.z, p2);
                    p3 = fmaf(o, w4.w, p3);
                }
            }
            #pragma unroll
            for (int off = 1; off < 64; off <<= 1) {
                p0 += __shfl_xor(p0, off);
                p1 += __shfl_xor(p1, off);
                p2 += __shfl_xor(p2, off);
                p3 += __shfl_xor(p3, off);
            }
            if (lane == 0) {
                float4 r;
                r.x = p0 + bout[0]; r.y = p1 + bout[1];
                r.z = p2 + bout[2]; r.w = p3 + bout[3];
                *(float4*)&out[(size_t)node * 4] = r;
            }
        }
    }
}

// ---------------------------------------------------------------------------
extern "C" void kernel_launch(void* const* d_in, const int* in_sizes, int n_in,
                              void* d_out, int out_size, void* d_ws, size_t ws_size,
                              hipStream_t stream) {
    const float* x  = (const float*)d_in[0];
    const int*   ei = (const int*)d_in[1];
    const float* Wl[3]  = {(const float*)d_in[2], (const float*)d_in[6],  (const float*)d_in[10]};
    const float* Wr[3]  = {(const float*)d_in[3], (const float*)d_in[7],  (const float*)d_in[11]};
    const float* att[3] = {(const float*)d_in[4], (const float*)d_in[8],  (const float*)d_in[12]};
    const float* bb[3]  = {(const float*)d_in[5], (const float*)d_in[9],  (const float*)d_in[13]};
    const float* Wout = (const float*)d_in[14];
    const float* bout = (const float*)d_in[15];

    int Nn   = in_sizes[0] / NCH;       // 20000
    int E    = in_sizes[1] / 2;         // 320000
    int Etot = E + Nn;

    size_t NEf = (size_t)Nn * NCH;
    __half* xlh  = (__half*)d_ws;                  // NEf
    float*  xr   = (float*)(xlh + NEf);            // NEf
    __half* pAhi = (__half*)(xr + NEf);            // NEf
    __half* pAlo = pAhi + NEf;
    __half* pBhi = pAlo + NEf;
    __half* pBlo = pBhi + NEf;
    __half* wt   = pBlo + NEf;                     // 6 * 65536
    int*   counts  = (int*)(wt + 6 * 65536);
    int*   offsets = counts + Nn;
    int*   cursor  = offsets + (Nn + 1);
    int*   csr_src = cursor + Nn;

    zero_kernel<<<(Nn + 255) / 256, 256, 0, stream>>>(counts, Nn);
    int eblocks = (Etot + 255) / 256;
    count_kernel<<<eblocks, 256, 0, stream>>>(ei, E, Nn, counts);
    scan_kernel<<<1, 1024, 0, stream>>>(counts, offsets, cursor, Nn);
    scatter_kernel<<<eblocks, 256, 0, stream>>>(ei, E, Nn, cursor, csr_src);

    WPtrs wp = {{Wl[0], Wr[0], Wl[1], Wr[1], Wl[2], Wr[2]}};
    wsplit_kernel<<<dim3(8, 8, 6), dim3(32, 32), 0, stream>>>(wp, wt);

    int n4 = (int)(NEf / 4);
    split_kernel<<<(n4 + 255) / 256, 256, 0, stream>>>(x, pAhi, pAlo, n4);

    int nrt = (Nn + 127) / 128;                    // 157 row tiles
    int prt = ((nrt + 7) / 8) * 8;                 // padded to 8
    int gblocks = prt * 4;                         // 640
    int nblocks = 2500;                            // 10000 waves = 2 nodes each
    if (nblocks > (Nn + 3) / 4) nblocks = (Nn + 3) / 4;

    __half* curHi = pAhi; __half* curLo = pAlo;
    __half* nxtHi = pBhi; __half* nxtLo = pBlo;
    for (int l = 0; l < 3; ++l) {
        dual_gemm_mfma<<<gblocks, 256, 0, stream>>>(
            curHi, curLo, wt + (size_t)l * 2 * 65536, xlh, xr, Nn);
        if (l < 2) {
            gat_agg7<0><<<nblocks, 256, 0, stream>>>(xlh, xr, att[l], bb[l],
                offsets, csr_src, nxtHi, nxtLo, nullptr, nullptr, nullptr, Nn);
        } else {
            gat_agg7<1><<<nblocks, 256, 0, stream>>>(xlh, xr, att[l], bb[l],
                offsets, csr_src, nullptr, nullptr, Wout, bout, (float*)d_out, Nn);
        }
        __half* th = curHi; __half* tl = curLo;
        curHi = nxtHi; curLo = nxtLo; nxtHi = th; nxtLo = tl;
    }
}

// Round 10
// 230.948 us; speedup vs baseline: 1.1629x; 1.1495x over previous
//
#include <hip/hip_runtime.h>
#include <hip/hip_bf16.h>
#include <hip/hip_fp16.h>
#include <math.h>

// N=20000, E=320000, layers: [N,256]@[256,256] GEMMs, HEADS=2, HID=128.
#define NCH 256
#define LEAKY 0.2f

typedef __attribute__((ext_vector_type(8))) _Float16 half8_t;  // 4 VGPRs
typedef __attribute__((ext_vector_type(2))) _Float16 half2_t;
typedef __attribute__((ext_vector_type(4))) float f32x4;       // MFMA C/D

static __device__ __forceinline__ half2_t u2h2(unsigned u) {
    return __builtin_bit_cast(half2_t, u);
}

// ---------------------------------------------------------------------------
// CSR build: zero -> counts -> scan -> scatter
// ---------------------------------------------------------------------------
__global__ void zero_kernel(int* __restrict__ p, int n) {
    int i = blockIdx.x * 256 + threadIdx.x;
    if (i < n) p[i] = 0;
}

__global__ void count_kernel(const int* __restrict__ ei, int E, int n,
                             int* __restrict__ counts) {
    int tid = blockIdx.x * 256 + threadIdx.x;
    int tot = E + n;
    if (tid >= tot) return;
    int dst = (tid < E) ? ei[E + tid] : (tid - E);
    atomicAdd(&counts[dst], 1);
}

__global__ void scan_kernel(const int* __restrict__ counts,
                            int* __restrict__ offsets,
                            int* __restrict__ cursor, int n) {
    __shared__ int wsum[16];
    int tid  = threadIdx.x;          // 1024 threads = 16 waves
    int lane = tid & 63, w = tid >> 6;
    int carry = 0;
    for (int base = 0; base < n; base += 1024) {
        int idx = base + tid;
        int v = (idx < n) ? counts[idx] : 0;
        int incl = v;
        #pragma unroll
        for (int off = 1; off < 64; off <<= 1) {
            int t2 = __shfl_up(incl, off, 64);
            if (lane >= off) incl += t2;
        }
        if (lane == 63) wsum[w] = incl;
        __syncthreads();
        if (w == 0 && lane < 16) {
            int s = wsum[lane];
            #pragma unroll
            for (int off = 1; off < 16; off <<= 1) {
                int t2 = __shfl_up(s, off, 64);
                if (lane >= off) s += t2;
            }
            wsum[lane] = s;
        }
        __syncthreads();
        int wpre = (w == 0) ? 0 : wsum[w - 1];
        int excl = carry + wpre + incl - v;
        if (idx < n) { offsets[idx] = excl; cursor[idx] = excl; }
        carry += wsum[15];
        __syncthreads();
    }
    if (tid == 0) offsets[n] = carry;
}

__global__ void scatter_kernel(const int* __restrict__ ei, int E, int n,
                               int* __restrict__ cursor,
                               int* __restrict__ csr_src) {
    int tid = blockIdx.x * 256 + threadIdx.x;
    int tot = E + n;
    if (tid >= tot) return;
    int src, dst;
    if (tid < E) { src = ei[tid]; dst = ei[E + tid]; }
    else         { src = dst = tid - E; }
    int pos = atomicAdd(&cursor[dst], 1);
    csr_src[pos] = src;
}

// ---------------------------------------------------------------------------
// fp32 -> fp16 hi/lo split (layer-1 input x only). hi+lo covers 22 bits.
// ---------------------------------------------------------------------------
__global__ void split_kernel(const float* __restrict__ in,
                             __half* __restrict__ hi, __half* __restrict__ lo,
                             int n4) {
    int i = blockIdx.x * 256 + threadIdx.x;
    if (i >= n4) return;
    float4 v = ((const float4*)in)[i];
    __half h0 = __float2half_rn(v.x), h1 = __float2half_rn(v.y);
    __half h2 = __float2half_rn(v.z), h3 = __float2half_rn(v.w);
    ushort4 hv = make_ushort4(__half_as_ushort(h0), __half_as_ushort(h1),
                              __half_as_ushort(h2), __half_as_ushort(h3));
    ushort4 lv = make_ushort4(
        __half_as_ushort(__float2half_rn(v.x - __half2float(h0))),
        __half_as_ushort(__float2half_rn(v.y - __half2float(h1))),
        __half_as_ushort(__float2half_rn(v.z - __half2float(h2))),
        __half_as_ushort(__float2half_rn(v.w - __half2float(h3))));
    ((ushort4*)hi)[i] = hv;
    ((ushort4*)lo)[i] = lv;
}

// ---------------------------------------------------------------------------
// Weight transpose: W[256,256] (k-major) -> Wt[256,256] (n-major) fp16.
// ---------------------------------------------------------------------------
struct WPtrs { const float* w[6]; };
__global__ __launch_bounds__(1024) void wsplit_kernel(WPtrs p,
        __half* __restrict__ wt) {
    __shared__ float tile[32][33];
    int m = blockIdx.z;
    const float* W = p.w[m];
    size_t base = (size_t)m * 65536;
    int k = blockIdx.y * 32 + threadIdx.y;
    int n = blockIdx.x * 32 + threadIdx.x;
    tile[threadIdx.y][threadIdx.x] = W[k * NCH + n];
    __syncthreads();
    int on = blockIdx.x * 32 + threadIdx.y;
    int ok = blockIdx.y * 32 + threadIdx.x;
    wt[base + (size_t)on * NCH + ok] = __float2half_rn(tile[threadIdx.x][threadIdx.y]);
}

// ---------------------------------------------------------------------------
// MFMA dual GEMM, fp16 2-product split: C = Ahi*B + Alo*B (B single fp16).
// Flat grid with L2-reuse swizzle (stripes of 32 = 8 row-tiles x 4 cbs).
// xl written fp16 (gather side), xr fp32.
// ---------------------------------------------------------------------------
#define LDK 40
__global__ __launch_bounds__(256) void dual_gemm_mfma(
        const __half* __restrict__ Ahi, const __half* __restrict__ Alo,
        const __half* __restrict__ Bt,
        __half* __restrict__ xlh, float* __restrict__ xr, int M) {
    __shared__ ushort As[2][128 * LDK];
    __shared__ ushort Bs[128 * LDK];
    int b = blockIdx.x;
    int stripe = b >> 5;
    int wslot  = b & 31;
    int rt = (stripe << 3) + (wslot & 7);
    int cb = wslot >> 3;
    int row0 = rt * 128;
    if (row0 >= M) return;
    const __half* Bm = Bt + (size_t)(cb >> 1) * 65536;
    int col0 = (cb & 1) * 128;
    int t = threadIdx.x;
    int lane = t & 63, w = t >> 6;
    int wr = w >> 1, wc = w & 1;
    int l15 = lane & 15, l4 = lane >> 4;

    f32x4 acc[4][4];
    #pragma unroll
    for (int i = 0; i < 4; ++i)
        #pragma unroll
        for (int j = 0; j < 4; ++j) acc[i][j] = (f32x4){0.f, 0.f, 0.f, 0.f};

    int r0 = t >> 2,          q0 = (t & 3) * 8;
    int r1 = (t + 256) >> 2,  q1 = ((t + 256) & 3) * 8;

    for (int k0 = 0; k0 < 256; k0 += 32) {
        uint4 z = make_uint4(0, 0, 0, 0);
        uint4 a0h = z, a0l = z, a1h = z, a1l = z;
        if (row0 + r0 < M) {
            a0h = *(const uint4*)&Ahi[(size_t)(row0 + r0) * NCH + k0 + q0];
            a0l = *(const uint4*)&Alo[(size_t)(row0 + r0) * NCH + k0 + q0];
        }
        if (row0 + r1 < M) {
            a1h = *(const uint4*)&Ahi[(size_t)(row0 + r1) * NCH + k0 + q1];
            a1l = *(const uint4*)&Alo[(size_t)(row0 + r1) * NCH + k0 + q1];
        }
        uint4 b0 = *(const uint4*)&Bm[(size_t)(col0 + r0) * NCH + k0 + q0];
        uint4 b1 = *(const uint4*)&Bm[(size_t)(col0 + r1) * NCH + k0 + q1];
        __syncthreads();
        *(uint4*)&As[0][r0 * LDK + q0] = a0h;
        *(uint4*)&As[1][r0 * LDK + q0] = a0l;
        *(uint4*)&As[0][r1 * LDK + q1] = a1h;
        *(uint4*)&As[1][r1 * LDK + q1] = a1l;
        *(uint4*)&Bs[r0 * LDK + q0] = b0;
        *(uint4*)&Bs[r1 * LDK + q1] = b1;
        __syncthreads();

        half8_t af[4][2], bq[4];
        #pragma unroll
        for (int fm = 0; fm < 4; ++fm) {
            int addr = (wr * 64 + fm * 16 + l15) * LDK + l4 * 8;
            af[fm][0] = *(const half8_t*)&As[0][addr];
            af[fm][1] = *(const half8_t*)&As[1][addr];
        }
        #pragma unroll
        for (int fn = 0; fn < 4; ++fn) {
            int addr = (wc * 64 + fn * 16 + l15) * LDK + l4 * 8;
            bq[fn] = *(const half8_t*)&Bs[addr];
        }
        #pragma unroll
        for (int fm = 0; fm < 4; ++fm)
            #pragma unroll
            for (int fn = 0; fn < 4; ++fn) {
                acc[fm][fn] = __builtin_amdgcn_mfma_f32_16x16x32_f16(
                    af[fm][0], bq[fn], acc[fm][fn], 0, 0, 0);
                acc[fm][fn] = __builtin_amdgcn_mfma_f32_16x16x32_f16(
                    af[fm][1], bq[fn], acc[fm][fn], 0, 0, 0);
            }
    }

    #pragma unroll
    for (int fm = 0; fm < 4; ++fm)
        #pragma unroll
        for (int fn = 0; fn < 4; ++fn) {
            int col = col0 + wc * 64 + fn * 16 + l15;
            #pragma unroll
            for (int r = 0; r < 4; ++r) {
                int row = row0 + wr * 64 + fm * 16 + l4 * 4 + r;
                if (row < M) {
                    if (cb < 2)
                        xlh[(size_t)row * NCH + col] = __float2half_rn(acc[fm][fn][r]);
                    else
                        xr[(size_t)row * NCH + col] = acc[fm][fn][r];
                }
            }
        }
}

// ---------------------------------------------------------------------------
// GAT aggregation (R7-proven structure): persistent grid-stride waves,
// half-wave pair layout, packed-fp16 dot (v_pk_* + v_dot2_f32_f16).
// lane = 32*el + l; el = edge-of-pair, l = channel-lane, channels [8l,8l+8).
// Heads: l 0..15 = head0, l 16..31 = head1 (4-step shfl reduce in 16 lanes).
// No software prefetch (R8 showed it regresses). Epilogue emits fp16 hi/lo.
// ---------------------------------------------------------------------------
static __device__ __forceinline__ float edge_dot(
        const uint4& r, const half2_t* xrh, const half2_t* atth) {
    const half2_t zh = (half2_t){(_Float16)0.f, (_Float16)0.f};
    const half2_t ch = (half2_t){(_Float16)LEAKY, (_Float16)LEAKY};
    float p = 0.f;
    #pragma unroll
    for (int q = 0; q < 4; ++q) {
        unsigned u = (&r.x)[q];
        half2_t t = u2h2(u) + xrh[q];
        half2_t m = __builtin_elementwise_max(t, zh) +
                    ch * __builtin_elementwise_min(t, zh);
        p = __builtin_amdgcn_fdot2(m, atth[q], p, false);
    }
    return p;
}

template <int LAST>
__global__ __launch_bounds__(256) void gat_agg8(
        const __half* __restrict__ xlh, const float* __restrict__ xr,
        const float* __restrict__ att, const float* __restrict__ bias,
        const int* __restrict__ offsets, const int* __restrict__ csr_src,
        __half* __restrict__ hhi, __half* __restrict__ hlo,
        const float* __restrict__ Wout, const float* __restrict__ bout,
        float* __restrict__ out, int nNodes) {
    int wid  = threadIdx.x >> 6;
    int lane = threadIdx.x & 63;
    int el = lane >> 5;
    int l  = lane & 31;
    int c0 = l * 8;

    half2_t atth[4];
    {
        float a8[8];
        *(float4*)&a8[0] = *(const float4*)&att[c0];
        *(float4*)&a8[4] = *(const float4*)&att[c0 + 4];
        #pragma unroll
        for (int q = 0; q < 4; ++q)
            atth[q] = (half2_t){(_Float16)a8[2 * q], (_Float16)a8[2 * q + 1]};
    }

    int stride = gridDim.x << 2;
    for (int node0 = (blockIdx.x << 2) + wid; node0 < nNodes; node0 += stride) {
        int node = __builtin_amdgcn_readfirstlane(node0);
        half2_t xrh[4];
        {
            float x8[8];
            *(float4*)&x8[0] = *(const float4*)&xr[(size_t)node * NCH + c0];
            *(float4*)&x8[4] = *(const float4*)&xr[(size_t)node * NCH + c0 + 4];
            #pragma unroll
            for (int q = 0; q < 4; ++q)
                xrh[q] = (half2_t){(_Float16)x8[2 * q], (_Float16)x8[2 * q + 1]};
        }

        int begin = offsets[node], end = offsets[node + 1];
        float denom = 0.f;
        float acc8[8];
        #pragma unroll
        for (int c = 0; c < 8; ++c) acc8[c] = 0.f;

        for (int j = begin; j < end; j += 4) {
            int j1 = j + 1 < end ? j + 1 : end - 1;
            int j2 = j + 2 < end ? j + 2 : end - 1;
            int j3 = j + 3 < end ? j + 3 : end - 1;
            int i0 = csr_src[j];
            int i1 = csr_src[j1];
            int i2 = csr_src[j2];
            int i3 = csr_src[j3];
            int sA = el ? i1 : i0;
            int sB = el ? i3 : i2;
            uint4 rA = *(const uint4*)&xlh[(size_t)sA * NCH + c0];
            uint4 rB = *(const uint4*)&xlh[(size_t)sB * NCH + c0];

            float pA = edge_dot(rA, xrh, atth);
            float pB = edge_dot(rB, xrh, atth);
            #pragma unroll
            for (int off = 1; off < 16; off <<= 1) {
                pA += __shfl_xor(pA, off);
                pB += __shfl_xor(pB, off);
            }
            float exA = (j + el < end)     ? __expf(pA) : 0.f;
            float exB = (j + 2 + el < end) ? __expf(pB) : 0.f;
            denom += exA + exB;
            #pragma unroll
            for (int q = 0; q < 4; ++q) {
                float2 fa = __half22float2(*(const __half2*)&(&rA.x)[q]);
                float2 fb = __half22float2(*(const __half2*)&(&rB.x)[q]);
                acc8[2 * q]     = fmaf(exA, fa.x, acc8[2 * q]);
                acc8[2 * q + 1] = fmaf(exA, fa.y, acc8[2 * q + 1]);
                acc8[2 * q]     = fmaf(exB, fb.x, acc8[2 * q]);
                acc8[2 * q + 1] = fmaf(exB, fb.y, acc8[2 * q + 1]);
            }
        }

        // combine edge-halves
        #pragma unroll
        for (int c = 0; c < 8; ++c) acc8[c] += __shfl_xor(acc8[c], 32);
        denom += __shfl_xor(denom, 32);
        float rd = 1.0f / denom;

        float o8[8], bi8[8];
        *(float4*)&bi8[0] = *(const float4*)&bias[c0];
        *(float4*)&bi8[4] = *(const float4*)&bias[c0 + 4];
        #pragma unroll
        for (int c = 0; c < 8; ++c)
            o8[c] = fmaxf(fmaf(acc8[c], rd, bi8[c]), 0.f);

        if (!LAST) {
            if (el == 0) {
                ushort h8[8], lo8[8];
                #pragma unroll
                for (int c = 0; c < 8; ++c) {
                    __half h = __float2half_rn(o8[c]);
                    h8[c]  = __half_as_ushort(h);
                    lo8[c] = __half_as_ushort(__float2half_rn(o8[c] - __half2float(h)));
                }
                *(uint4*)&hhi[(size_t)node * NCH + c0] = *(uint4*)&h8[0];
                *(uint4*)&hlo[(size_t)node * NCH + c0] = *(uint4*)&lo8[0];
            }
        } else {
            float p0 = 0.f, p1 = 0.f, p2 = 0.f, p3 = 0.f;
            #pragma unroll
            for (int c = 0; c < 8; ++c) {
                float4 w4 = *(const float4*)&Wout[(size_t)(c0 + c) * 4];
                p0 = fmaf(o8[c], w4.x, p0);
                p1 = fmaf(o8[c], w4.y, p1);
                p2 = fmaf(o8[c], w4.z, p2);
                p3 = fmaf(o8[c], w4.w, p3);
            }
            #pragma unroll
            for (int off = 1; off < 32; off <<= 1) {
                p0 += __shfl_xor(p0, off);
                p1 += __shfl_xor(p1, off);
                p2 += __shfl_xor(p2, off);
                p3 += __shfl_xor(p3, off);
            }
            if (lane == 0) {
                float4 r;
                r.x = p0 + bout[0]; r.y = p1 + bout[1];
                r.z = p2 + bout[2]; r.w = p3 + bout[3];
                *(float4*)&out[(size_t)node * 4] = r;
            }
        }
    }
}

// ---------------------------------------------------------------------------
extern "C" void kernel_launch(void* const* d_in, const int* in_sizes, int n_in,
                              void* d_out, int out_size, void* d_ws, size_t ws_size,
                              hipStream_t stream) {
    const float* x  = (const float*)d_in[0];
    const int*   ei = (const int*)d_in[1];
    const float* Wl[3]  = {(const float*)d_in[2], (const float*)d_in[6],  (const float*)d_in[10]};
    const float* Wr[3]  = {(const float*)d_in[3], (const float*)d_in[7],  (const float*)d_in[11]};
    const float* att[3] = {(const float*)d_in[4], (const float*)d_in[8],  (const float*)d_in[12]};
    const float* bb[3]  = {(const float*)d_in[5], (const float*)d_in[9],  (const float*)d_in[13]};
    const float* Wout = (const float*)d_in[14];
    const float* bout = (const float*)d_in[15];

    int Nn   = in_sizes[0] / NCH;       // 20000
    int E    = in_sizes[1] / 2;         // 320000
    int Etot = E + Nn;

    size_t NEf = (size_t)Nn * NCH;
    __half* xlh  = (__half*)d_ws;                  // NEf
    float*  xr   = (float*)(xlh + NEf);            // NEf
    __half* pAhi = (__half*)(xr + NEf);            // NEf
    __half* pAlo = pAhi + NEf;
    __half* pBhi = pAlo + NEf;
    __half* pBlo = pBhi + NEf;
    __half* wt   = pBlo + NEf;                     // 6 * 65536
    int*   counts  = (int*)(wt + 6 * 65536);
    int*   offsets = counts + Nn;
    int*   cursor  = offsets + (Nn + 1);
    int*   csr_src = cursor + Nn;

    zero_kernel<<<(Nn + 255) / 256, 256, 0, stream>>>(counts, Nn);
    int eblocks = (Etot + 255) / 256;
    count_kernel<<<eblocks, 256, 0, stream>>>(ei, E, Nn, counts);
    scan_kernel<<<1, 1024, 0, stream>>>(counts, offsets, cursor, Nn);
    scatter_kernel<<<eblocks, 256, 0, stream>>>(ei, E, Nn, cursor, csr_src);

    WPtrs wp = {{Wl[0], Wr[0], Wl[1], Wr[1], Wl[2], Wr[2]}};
    wsplit_kernel<<<dim3(8, 8, 6), dim3(32, 32), 0, stream>>>(wp, wt);

    int n4 = (int)(NEf / 4);
    split_kernel<<<(n4 + 255) / 256, 256, 0, stream>>>(x, pAhi, pAlo, n4);

    int nrt = (Nn + 127) / 128;                    // 157 row tiles
    int prt = ((nrt + 7) / 8) * 8;                 // padded to 8
    int gblocks = prt * 4;                         // 640
    int nblocks = 2048;                            // R7-proven grid
    if (nblocks > (Nn + 3) / 4) nblocks = (Nn + 3) / 4;

    __half* curHi = pAhi; __half* curLo = pAlo;
    __half* nxtHi = pBhi; __half* nxtLo = pBlo;
    for (int l = 0; l < 3; ++l) {
        dual_gemm_mfma<<<gblocks, 256, 0, stream>>>(
            curHi, curLo, wt + (size_t)l * 2 * 65536, xlh, xr, Nn);
        if (l < 2) {
            gat_agg8<0><<<nblocks, 256, 0, stream>>>(xlh, xr, att[l], bb[l],
                offsets, csr_src, nxtHi, nxtLo, nullptr, nullptr, nullptr, Nn);
        } else {
            gat_agg8<1><<<nblocks, 256, 0, stream>>>(xlh, xr, att[l], bb[l],
                offsets, csr_src, nullptr, nullptr, Wout, bout, (float*)d_out, Nn);
        }
        __half* th = curHi; __half* tl = curLo;
        curHi = nxtHi; curLo = nxtLo; nxtHi = th; nxtLo = tl;
    }
}

// Round 11
// 212.020 us; speedup vs baseline: 1.2667x; 1.0893x over previous
//
#include <hip/hip_runtime.h>
#include <hip/hip_bf16.h>
#include <hip/hip_fp16.h>
#include <math.h>

// N=20000, E=320000, layers: [N,256]@[256,256] GEMMs, HEADS=2, HID=128.
#define NCH 256
#define LEAKY 0.2f

typedef __attribute__((ext_vector_type(8))) _Float16 half8_t;  // 4 VGPRs
typedef __attribute__((ext_vector_type(2))) _Float16 half2_t;
typedef __attribute__((ext_vector_type(4))) float f32x4;       // MFMA C/D

static __device__ __forceinline__ half2_t u2h2(unsigned u) {
    return __builtin_bit_cast(half2_t, u);
}

// pack 8 fp32 -> fp16 hi + fp16 lo (hi+lo covers 22 mantissa bits)
static __device__ __forceinline__ void f32_to_hl8(const float4 a, const float4 b,
                                                  uint4& h, uint4& l) {
    float f[8] = {a.x, a.y, a.z, a.w, b.x, b.y, b.z, b.w};
    unsigned hs[8], ls[8];
    #pragma unroll
    for (int c = 0; c < 8; ++c) {
        __half hh = __float2half_rn(f[c]);
        hs[c] = __half_as_ushort(hh);
        ls[c] = __half_as_ushort(__float2half_rn(f[c] - __half2float(hh)));
    }
    h = make_uint4(hs[0] | (hs[1] << 16), hs[2] | (hs[3] << 16),
                   hs[4] | (hs[5] << 16), hs[6] | (hs[7] << 16));
    l = make_uint4(ls[0] | (ls[1] << 16), ls[2] | (ls[3] << 16),
                   ls[4] | (ls[5] << 16), ls[6] | (ls[7] << 16));
}

// ---------------------------------------------------------------------------
// CSR build: zero -> counts (int4-vectorized) -> scan (4 elem/thread)
//            -> scatter (int4-vectorized)
// ---------------------------------------------------------------------------
__global__ void zero_kernel(int* __restrict__ p, int n) {
    int i = blockIdx.x * 256 + threadIdx.x;
    if (i < n) p[i] = 0;
}

__global__ void count_kernel(const int* __restrict__ ei, int E, int n,
                             int* __restrict__ counts) {
    int tid = blockIdx.x * 256 + threadIdx.x;
    int E4 = E >> 2;                    // E divisible by 4 here (320000)
    if (tid < E4) {
        int4 d = ((const int4*)(ei + E))[tid];
        atomicAdd(&counts[d.x], 1);
        atomicAdd(&counts[d.y], 1);
        atomicAdd(&counts[d.z], 1);
        atomicAdd(&counts[d.w], 1);
    } else {
        int s = tid - E4;               // self loops
        if (s < n) atomicAdd(&counts[s], 1);
    }
}

__global__ void scan_kernel(const int* __restrict__ counts,
                            int* __restrict__ offsets,
                            int* __restrict__ cursor, int n) {
    __shared__ int wsum[16];
    int tid  = threadIdx.x;          // 1024 threads = 16 waves, 4 elem/thread
    int lane = tid & 63, w = tid >> 6;
    int carry = 0;
    for (int base = 0; base < n; base += 4096) {
        int i0 = base + tid * 4;
        int v0 = 0, v1 = 0, v2 = 0, v3 = 0;
        if (i0 + 3 < n) {
            int4 v = *(const int4*)&counts[i0];
            v0 = v.x; v1 = v.y; v2 = v.z; v3 = v.w;
        } else if (i0 < n) {
            v0 = counts[i0];
            if (i0 + 1 < n) v1 = counts[i0 + 1];
            if (i0 + 2 < n) v2 = counts[i0 + 2];
        }
        int c1 = v0 + v1, c2 = c1 + v2, c3 = c2 + v3;
        int tsum = c3;
        int incl = tsum;
        #pragma unroll
        for (int off = 1; off < 64; off <<= 1) {
            int t2 = __shfl_up(incl, off, 64);
            if (lane >= off) incl += t2;
        }
        if (lane == 63) wsum[w] = incl;
        __syncthreads();
        if (w == 0 && lane < 16) {
            int s = wsum[lane];
            #pragma unroll
            for (int off = 1; off < 16; off <<= 1) {
                int t2 = __shfl_up(s, off, 64);
                if (lane >= off) s += t2;
            }
            wsum[lane] = s;
        }
        __syncthreads();
        int wpre = (w == 0) ? 0 : wsum[w - 1];
        int excl = carry + wpre + incl - tsum;
        if (i0 + 3 < n) {
            int4 o = make_int4(excl, excl + v0, excl + c1, excl + c2);
            *(int4*)&offsets[i0] = o;
            *(int4*)&cursor[i0]  = o;
        } else if (i0 < n) {
            offsets[i0] = excl;           cursor[i0] = excl;
            if (i0 + 1 < n) { offsets[i0 + 1] = excl + v0; cursor[i0 + 1] = excl + v0; }
            if (i0 + 2 < n) { offsets[i0 + 2] = excl + c1; cursor[i0 + 2] = excl + c1; }
        }
        carry += wsum[15];
        __syncthreads();
    }
    if (tid == 0) offsets[n] = carry;
}

__global__ void scatter_kernel(const int* __restrict__ ei, int E, int n,
                               int* __restrict__ cursor,
                               int* __restrict__ csr_src) {
    int tid = blockIdx.x * 256 + threadIdx.x;
    int E4 = E >> 2;
    if (tid < E4) {
        int4 s = ((const int4*)ei)[tid];
        int4 d = ((const int4*)(ei + E))[tid];
        csr_src[atomicAdd(&cursor[d.x], 1)] = s.x;
        csr_src[atomicAdd(&cursor[d.y], 1)] = s.y;
        csr_src[atomicAdd(&cursor[d.z], 1)] = s.z;
        csr_src[atomicAdd(&cursor[d.w], 1)] = s.w;
    } else {
        int i = tid - E4;               // self loops
        if (i < n) csr_src[atomicAdd(&cursor[i], 1)] = i;
    }
}

// ---------------------------------------------------------------------------
// Weight transpose: W[256,256] (k-major) -> Wt[256,256] (n-major) fp16.
// ---------------------------------------------------------------------------
struct WPtrs { const float* w[6]; };
__global__ __launch_bounds__(1024) void wsplit_kernel(WPtrs p,
        __half* __restrict__ wt) {
    __shared__ float tile[32][33];
    int m = blockIdx.z;
    const float* W = p.w[m];
    size_t base = (size_t)m * 65536;
    int k = blockIdx.y * 32 + threadIdx.y;
    int n = blockIdx.x * 32 + threadIdx.x;
    tile[threadIdx.y][threadIdx.x] = W[k * NCH + n];
    __syncthreads();
    int on = blockIdx.x * 32 + threadIdx.y;
    int ok = blockIdx.y * 32 + threadIdx.x;
    wt[base + (size_t)on * NCH + ok] = __float2half_rn(tile[threadIdx.x][threadIdx.y]);
}

// ---------------------------------------------------------------------------
// MFMA dual GEMM, fp16 2-product split: C = Ahi*B + Alo*B (B single fp16).
// AF32: A is fp32 (layer 1), hi/lo split happens in-register during staging.
// Flat grid with L2-reuse swizzle (stripes of 32 = 8 row-tiles x 4 cbs).
// xl written fp16 (gather side), xr fp32.
// ---------------------------------------------------------------------------
#define LDK 40
template <int AF32>
__global__ __launch_bounds__(256) void dual_gemm_mfma(
        const float* __restrict__ Af,
        const __half* __restrict__ Ahi, const __half* __restrict__ Alo,
        const __half* __restrict__ Bt,
        __half* __restrict__ xlh, float* __restrict__ xr, int M) {
    __shared__ ushort As[2][128 * LDK];
    __shared__ ushort Bs[128 * LDK];
    int b = blockIdx.x;
    int stripe = b >> 5;
    int wslot  = b & 31;
    int rt = (stripe << 3) + (wslot & 7);
    int cb = wslot >> 3;
    int row0 = rt * 128;
    if (row0 >= M) return;
    const __half* Bm = Bt + (size_t)(cb >> 1) * 65536;
    int col0 = (cb & 1) * 128;
    int t = threadIdx.x;
    int lane = t & 63, w = t >> 6;
    int wr = w >> 1, wc = w & 1;
    int l15 = lane & 15, l4 = lane >> 4;

    f32x4 acc[4][4];
    #pragma unroll
    for (int i = 0; i < 4; ++i)
        #pragma unroll
        for (int j = 0; j < 4; ++j) acc[i][j] = (f32x4){0.f, 0.f, 0.f, 0.f};

    int r0 = t >> 2,          q0 = (t & 3) * 8;
    int r1 = (t + 256) >> 2,  q1 = ((t + 256) & 3) * 8;

    for (int k0 = 0; k0 < 256; k0 += 32) {
        uint4 z = make_uint4(0, 0, 0, 0);
        uint4 a0h = z, a0l = z, a1h = z, a1l = z;
        if (row0 + r0 < M) {
            if (AF32) {
                float4 fa = *(const float4*)&Af[(size_t)(row0 + r0) * NCH + k0 + q0];
                float4 fb = *(const float4*)&Af[(size_t)(row0 + r0) * NCH + k0 + q0 + 4];
                f32_to_hl8(fa, fb, a0h, a0l);
            } else {
                a0h = *(const uint4*)&Ahi[(size_t)(row0 + r0) * NCH + k0 + q0];
                a0l = *(const uint4*)&Alo[(size_t)(row0 + r0) * NCH + k0 + q0];
            }
        }
        if (row0 + r1 < M) {
            if (AF32) {
                float4 fa = *(const float4*)&Af[(size_t)(row0 + r1) * NCH + k0 + q1];
                float4 fb = *(const float4*)&Af[(size_t)(row0 + r1) * NCH + k0 + q1 + 4];
                f32_to_hl8(fa, fb, a1h, a1l);
            } else {
                a1h = *(const uint4*)&Ahi[(size_t)(row0 + r1) * NCH + k0 + q1];
                a1l = *(const uint4*)&Alo[(size_t)(row0 + r1) * NCH + k0 + q1];
            }
        }
        uint4 b0 = *(const uint4*)&Bm[(size_t)(col0 + r0) * NCH + k0 + q0];
        uint4 b1 = *(const uint4*)&Bm[(size_t)(col0 + r1) * NCH + k0 + q1];
        __syncthreads();
        *(uint4*)&As[0][r0 * LDK + q0] = a0h;
        *(uint4*)&As[1][r0 * LDK + q0] = a0l;
        *(uint4*)&As[0][r1 * LDK + q1] = a1h;
        *(uint4*)&As[1][r1 * LDK + q1] = a1l;
        *(uint4*)&Bs[r0 * LDK + q0] = b0;
        *(uint4*)&Bs[r1 * LDK + q1] = b1;
        __syncthreads();

        half8_t af[4][2], bq[4];
        #pragma unroll
        for (int fm = 0; fm < 4; ++fm) {
            int addr = (wr * 64 + fm * 16 + l15) * LDK + l4 * 8;
            af[fm][0] = *(const half8_t*)&As[0][addr];
            af[fm][1] = *(const half8_t*)&As[1][addr];
        }
        #pragma unroll
        for (int fn = 0; fn < 4; ++fn) {
            int addr = (wc * 64 + fn * 16 + l15) * LDK + l4 * 8;
            bq[fn] = *(const half8_t*)&Bs[addr];
        }
        #pragma unroll
        for (int fm = 0; fm < 4; ++fm)
            #pragma unroll
            for (int fn = 0; fn < 4; ++fn) {
                acc[fm][fn] = __builtin_amdgcn_mfma_f32_16x16x32_f16(
                    af[fm][0], bq[fn], acc[fm][fn], 0, 0, 0);
                acc[fm][fn] = __builtin_amdgcn_mfma_f32_16x16x32_f16(
                    af[fm][1], bq[fn], acc[fm][fn], 0, 0, 0);
            }
    }

    #pragma unroll
    for (int fm = 0; fm < 4; ++fm)
        #pragma unroll
        for (int fn = 0; fn < 4; ++fn) {
            int col = col0 + wc * 64 + fn * 16 + l15;
            #pragma unroll
            for (int r = 0; r < 4; ++r) {
                int row = row0 + wr * 64 + fm * 16 + l4 * 4 + r;
                if (row < M) {
                    if (cb < 2)
                        xlh[(size_t)row * NCH + col] = __float2half_rn(acc[fm][fn][r]);
                    else
                        xr[(size_t)row * NCH + col] = acc[fm][fn][r];
                }
            }
        }
}

// ---------------------------------------------------------------------------
// GAT aggregation (R7/R10-proven structure, frozen): persistent grid-stride
// waves, half-wave pair layout, packed-fp16 dot. lane = 32*el + l,
// channels [8l,8l+8); heads l 0..15 / 16..31; 4-step shfl reduce.
// ---------------------------------------------------------------------------
static __device__ __forceinline__ float edge_dot(
        const uint4& r, const half2_t* xrh, const half2_t* atth) {
    const half2_t zh = (half2_t){(_Float16)0.f, (_Float16)0.f};
    const half2_t ch = (half2_t){(_Float16)LEAKY, (_Float16)LEAKY};
    float p = 0.f;
    #pragma unroll
    for (int q = 0; q < 4; ++q) {
        unsigned u = (&r.x)[q];
        half2_t t = u2h2(u) + xrh[q];
        half2_t m = __builtin_elementwise_max(t, zh) +
                    ch * __builtin_elementwise_min(t, zh);
        p = __builtin_amdgcn_fdot2(m, atth[q], p, false);
    }
    return p;
}

template <int LAST>
__global__ __launch_bounds__(256) void gat_agg8(
        const __half* __restrict__ xlh, const float* __restrict__ xr,
        const float* __restrict__ att, const float* __restrict__ bias,
        const int* __restrict__ offsets, const int* __restrict__ csr_src,
        __half* __restrict__ hhi, __half* __restrict__ hlo,
        const float* __restrict__ Wout, const float* __restrict__ bout,
        float* __restrict__ out, int nNodes) {
    int wid  = threadIdx.x >> 6;
    int lane = threadIdx.x & 63;
    int el = lane >> 5;
    int l  = lane & 31;
    int c0 = l * 8;

    half2_t atth[4];
    {
        float a8[8];
        *(float4*)&a8[0] = *(const float4*)&att[c0];
        *(float4*)&a8[4] = *(const float4*)&att[c0 + 4];
        #pragma unroll
        for (int q = 0; q < 4; ++q)
            atth[q] = (half2_t){(_Float16)a8[2 * q], (_Float16)a8[2 * q + 1]};
    }

    int stride = gridDim.x << 2;
    for (int node0 = (blockIdx.x << 2) + wid; node0 < nNodes; node0 += stride) {
        int node = __builtin_amdgcn_readfirstlane(node0);
        half2_t xrh[4];
        {
            float x8[8];
            *(float4*)&x8[0] = *(const float4*)&xr[(size_t)node * NCH + c0];
            *(float4*)&x8[4] = *(const float4*)&xr[(size_t)node * NCH + c0 + 4];
            #pragma unroll
            for (int q = 0; q < 4; ++q)
                xrh[q] = (half2_t){(_Float16)x8[2 * q], (_Float16)x8[2 * q + 1]};
        }

        int begin = offsets[node], end = offsets[node + 1];
        float denom = 0.f;
        float acc8[8];
        #pragma unroll
        for (int c = 0; c < 8; ++c) acc8[c] = 0.f;

        for (int j = begin; j < end; j += 4) {
            int j1 = j + 1 < end ? j + 1 : end - 1;
            int j2 = j + 2 < end ? j + 2 : end - 1;
            int j3 = j + 3 < end ? j + 3 : end - 1;
            int i0 = csr_src[j];
            int i1 = csr_src[j1];
            int i2 = csr_src[j2];
            int i3 = csr_src[j3];
            int sA = el ? i1 : i0;
            int sB = el ? i3 : i2;
            uint4 rA = *(const uint4*)&xlh[(size_t)sA * NCH + c0];
            uint4 rB = *(const uint4*)&xlh[(size_t)sB * NCH + c0];

            float pA = edge_dot(rA, xrh, atth);
            float pB = edge_dot(rB, xrh, atth);
            #pragma unroll
            for (int off = 1; off < 16; off <<= 1) {
                pA += __shfl_xor(pA, off);
                pB += __shfl_xor(pB, off);
            }
            float exA = (j + el < end)     ? __expf(pA) : 0.f;
            float exB = (j + 2 + el < end) ? __expf(pB) : 0.f;
            denom += exA + exB;
            #pragma unroll
            for (int q = 0; q < 4; ++q) {
                float2 fa = __half22float2(*(const __half2*)&(&rA.x)[q]);
                float2 fb = __half22float2(*(const __half2*)&(&rB.x)[q]);
                acc8[2 * q]     = fmaf(exA, fa.x, acc8[2 * q]);
                acc8[2 * q + 1] = fmaf(exA, fa.y, acc8[2 * q + 1]);
                acc8[2 * q]     = fmaf(exB, fb.x, acc8[2 * q]);
                acc8[2 * q + 1] = fmaf(exB, fb.y, acc8[2 * q + 1]);
            }
        }

        // combine edge-halves
        #pragma unroll
        for (int c = 0; c < 8; ++c) acc8[c] += __shfl_xor(acc8[c], 32);
        denom += __shfl_xor(denom, 32);
        float rd = 1.0f / denom;

        float o8[8], bi8[8];
        *(float4*)&bi8[0] = *(const float4*)&bias[c0];
        *(float4*)&bi8[4] = *(const float4*)&bias[c0 + 4];
        #pragma unroll
        for (int c = 0; c < 8; ++c)
            o8[c] = fmaxf(fmaf(acc8[c], rd, bi8[c]), 0.f);

        if (!LAST) {
            if (el == 0) {
                ushort h8[8], lo8[8];
                #pragma unroll
                for (int c = 0; c < 8; ++c) {
                    __half h = __float2half_rn(o8[c]);
                    h8[c]  = __half_as_ushort(h);
                    lo8[c] = __half_as_ushort(__float2half_rn(o8[c] - __half2float(h)));
                }
                *(uint4*)&hhi[(size_t)node * NCH + c0] = *(uint4*)&h8[0];
                *(uint4*)&hlo[(size_t)node * NCH + c0] = *(uint4*)&lo8[0];
            }
        } else {
            float p0 = 0.f, p1 = 0.f, p2 = 0.f, p3 = 0.f;
            #pragma unroll
            for (int c = 0; c < 8; ++c) {
                float4 w4 = *(const float4*)&Wout[(size_t)(c0 + c) * 4];
                p0 = fmaf(o8[c], w4.x, p0);
                p1 = fmaf(o8[c], w4.y, p1);
                p2 = fmaf(o8[c], w4.z, p2);
                p3 = fmaf(o8[c], w4.w, p3);
            }
            #pragma unroll
            for (int off = 1; off < 32; off <<= 1) {
                p0 += __shfl_xor(p0, off);
                p1 += __shfl_xor(p1, off);
                p2 += __shfl_xor(p2, off);
                p3 += __shfl_xor(p3, off);
            }
            if (lane == 0) {
                float4 r;
                r.x = p0 + bout[0]; r.y = p1 + bout[1];
                r.z = p2 + bout[2]; r.w = p3 + bout[3];
                *(float4*)&out[(size_t)node * 4] = r;
            }
        }
    }
}

// ---------------------------------------------------------------------------
extern "C" void kernel_launch(void* const* d_in, const int* in_sizes, int n_in,
                              void* d_out, int out_size, void* d_ws, size_t ws_size,
                              hipStream_t stream) {
    const float* x  = (const float*)d_in[0];
    const int*   ei = (const int*)d_in[1];
    const float* Wl[3]  = {(const float*)d_in[2], (const float*)d_in[6],  (const float*)d_in[10]};
    const float* Wr[3]  = {(const float*)d_in[3], (const float*)d_in[7],  (const float*)d_in[11]};
    const float* att[3] = {(const float*)d_in[4], (const float*)d_in[8],  (const float*)d_in[12]};
    const float* bb[3]  = {(const float*)d_in[5], (const float*)d_in[9],  (const float*)d_in[13]};
    const float* Wout = (const float*)d_in[14];
    const float* bout = (const float*)d_in[15];

    int Nn   = in_sizes[0] / NCH;       // 20000
    int E    = in_sizes[1] / 2;         // 320000

    size_t NEf = (size_t)Nn * NCH;
    __half* xlh  = (__half*)d_ws;                  // NEf
    float*  xr   = (float*)(xlh + NEf);            // NEf
    __half* bAhi = (__half*)(xr + NEf);            // NEf
    __half* bAlo = bAhi + NEf;
    __half* bBhi = bAlo + NEf;
    __half* bBlo = bBhi + NEf;
    __half* wt   = bBlo + NEf;                     // 6 * 65536
    int*   counts  = (int*)(wt + 6 * 65536);
    int*   offsets = counts + Nn;
    int*   cursor  = offsets + (Nn + 1);
    int*   csr_src = cursor + Nn;

    zero_kernel<<<(Nn + 255) / 256, 256, 0, stream>>>(counts, Nn);
    int vthreads = (E >> 2) + Nn;                  // vectorized edges + self loops
    int vblocks  = (vthreads + 255) / 256;
    count_kernel<<<vblocks, 256, 0, stream>>>(ei, E, Nn, counts);
    scan_kernel<<<1, 1024, 0, stream>>>(counts, offsets, cursor, Nn);
    scatter_kernel<<<vblocks, 256, 0, stream>>>(ei, E, Nn, cursor, csr_src);

    WPtrs wp = {{Wl[0], Wr[0], Wl[1], Wr[1], Wl[2], Wr[2]}};
    wsplit_kernel<<<dim3(8, 8, 6), dim3(32, 32), 0, stream>>>(wp, wt);

    int nrt = (Nn + 127) / 128;                    // 157 row tiles
    int prt = ((nrt + 7) / 8) * 8;                 // padded to 8
    int gblocks = prt * 4;                         // 640
    int nblocks = 2048;                            // proven gat grid
    if (nblocks > (Nn + 3) / 4) nblocks = (Nn + 3) / 4;

    // layer 1: A = x (fp32, split in-register)
    dual_gemm_mfma<1><<<gblocks, 256, 0, stream>>>(x, nullptr, nullptr,
                                                   wt, xlh, xr, Nn);
    gat_agg8<0><<<nblocks, 256, 0, stream>>>(xlh, xr, att[0], bb[0],
        offsets, csr_src, bAhi, bAlo, nullptr, nullptr, nullptr, Nn);
    // layer 2: A = bufA (fp16 hi/lo)
    dual_gemm_mfma<0><<<gblocks, 256, 0, stream>>>(nullptr, bAhi, bAlo,
                                                   wt + 2 * 65536, xlh, xr, Nn);
    gat_agg8<0><<<nblocks, 256, 0, stream>>>(xlh, xr, att[1], bb[1],
        offsets, csr_src, bBhi, bBlo, nullptr, nullptr, nullptr, Nn);
    // layer 3: A = bufB, fused output projection
    dual_gemm_mfma<0><<<gblocks, 256, 0, stream>>>(nullptr, bBhi, bBlo,
                                                   wt + 4 * 65536, xlh, xr, Nn);
    gat_agg8<1><<<nblocks, 256, 0, stream>>>(xlh, xr, att[2], bb[2],
        offsets, csr_src, nullptr, nullptr, Wout, bout, (float*)d_out, Nn);
}